// Round 1
// baseline (137.158 us; speedup 1.0000x reference)
//
#include <hip/hip_runtime.h>

#define NN 4096
#define HID 512
#define DD 64
#define SLOPE 0.2f
#define CH 64
#define CL 64   // NN/CH

// ---------------- k1: xt = x@W (f32, LDS-staged W), s1 = xt@a1, s2 = xt@a2 ----
__global__ __launch_bounds__(256) void k1_xt(
    const float* __restrict__ x, const float* __restrict__ W,
    const float* __restrict__ a,
    float* __restrict__ xt, float* __restrict__ s1, float* __restrict__ s2) {
  __shared__ float Wl[HID * DD];           // 128 KiB
  int tid = threadIdx.x;
  const float4* W4 = (const float4*)W;
  float4* Wl4 = (float4*)Wl;
#pragma unroll
  for (int u = 0; u < (HID * DD / 4) / 256; ++u)
    Wl4[u * 256 + tid] = W4[u * 256 + tid];
  __syncthreads();
  int wave = tid >> 6, lane = tid & 63;
  int base = blockIdx.x * 16 + wave * 4;   // 16 rows/block, 4 rows/wave
  for (int rr = 0; rr < 4; ++rr) {
    int i = base + rr;
    const float4* x4 = (const float4*)(x + i * HID);
    float acc = 0.f;
#pragma unroll 8
    for (int k4 = 0; k4 < HID / 4; ++k4) {
      float4 xv = x4[k4];
      int k = k4 * 4;
      acc = fmaf(xv.x, Wl[(k + 0) * DD + lane], acc);
      acc = fmaf(xv.y, Wl[(k + 1) * DD + lane], acc);
      acc = fmaf(xv.z, Wl[(k + 2) * DD + lane], acc);
      acc = fmaf(xv.w, Wl[(k + 3) * DD + lane], acc);
    }
    xt[i * DD + lane] = acc;
    float p1 = acc * a[lane];
    float p2 = acc * a[DD + lane];
#pragma unroll
    for (int off = 32; off >= 1; off >>= 1) {
      p1 += __shfl_xor(p1, off, 64);
      p2 += __shfl_xor(p2, off, 64);
    }
    if (lane == 0) { s1[i] = p1; s2[i] = p2; }
  }
}

// ---------------- k2: bitonic sort of s2 with permutation (single block) -----
__global__ __launch_bounds__(1024) void k2_sort(
    const float* __restrict__ s2, float* __restrict__ s2s, int* __restrict__ perm) {
  __shared__ float v[NN];
  __shared__ int ix[NN];
  int tid = threadIdx.x;
#pragma unroll
  for (int u = 0; u < NN / 1024; ++u) {
    int i = u * 1024 + tid;
    v[i] = s2[i]; ix[i] = i;
  }
  __syncthreads();
  for (int k = 2; k <= NN; k <<= 1) {
    for (int j = k >> 1; j > 0; j >>= 1) {
#pragma unroll
      for (int u = 0; u < NN / 1024; ++u) {
        int i = u * 1024 + tid;
        int p = i ^ j;
        if (p > i) {
          bool up = ((i & k) == 0);
          float av = v[i], bv = v[p];
          bool sw = up ? (av > bv) : (av < bv);
          if (sw) {
            v[i] = bv; v[p] = av;
            int t = ix[i]; ix[i] = ix[p]; ix[p] = t;
          }
        }
      }
      __syncthreads();
    }
  }
#pragma unroll
  for (int u = 0; u < NN / 1024; ++u) {
    int i = u * 1024 + tid;
    s2s[i] = v[i]; perm[i] = ix[i];
  }
}

// ---------------- k3: within-chunk inclusive scans (sorted order) ------------
// SP[r][d] = sum_{r' in chunk, r'<=r} exp(s2s[r']) * xt[perm[r']][d]
// SN[r][d] = same with exp(SLOPE*s2s), zP/zN scalar versions.
__global__ __launch_bounds__(64) void k3_scan(
    const float* __restrict__ xt, const float* __restrict__ s2s,
    const int* __restrict__ perm,
    float* __restrict__ SP, float* __restrict__ SN,
    float* __restrict__ zP, float* __restrict__ zN) {
  int lane = threadIdx.x;
  int r0 = blockIdx.x * CL;
  float aP = 0.f, aN = 0.f, aZP = 0.f, aZN = 0.f;
#pragma unroll 4
  for (int q = 0; q < CL; ++q) {
    int r = r0 + q;
    float sv = s2s[r];
    float eP = expf(sv);
    float eN = expf(SLOPE * sv);
    int p = perm[r];
    float xv = xt[p * DD + lane];
    aP = fmaf(eP, xv, aP);
    aN = fmaf(eN, xv, aN);
    aZP += eP; aZN += eN;
    SP[r * DD + lane] = aP;
    SN[r * DD + lane] = aN;
    if (lane == 0) { zP[r] = aZP; zN[r] = aZN; }
  }
}

// ---------------- k4: exclusive scan of chunk totals -------------------------
__global__ __launch_bounds__(64) void k4_off(
    const float* __restrict__ SP, const float* __restrict__ SN,
    const float* __restrict__ zP, const float* __restrict__ zN,
    float* __restrict__ offP, float* __restrict__ offN,
    float* __restrict__ offZP, float* __restrict__ offZN,
    float* __restrict__ totP, float* __restrict__ totZP) {
  int lane = threadIdx.x;
  float rP = 0.f, rN = 0.f, rZP = 0.f, rZN = 0.f;
  for (int c = 0; c < CH; ++c) {
    offP[c * DD + lane] = rP;
    offN[c * DD + lane] = rN;
    if (lane == 0) { offZP[c] = rZP; offZN[c] = rZN; }
    int last = c * CL + CL - 1;
    rP += SP[last * DD + lane];
    rN += SN[last * DD + lane];
    rZP += zP[last];
    rZN += zN[last];
  }
  totP[lane] = rP;
  if (lane == 0) totZP[0] = rZP;
}

// ---------------- k5: per-row binary search + closed-form output -------------
__global__ __launch_bounds__(256) void k5_out(
    const float* __restrict__ s1, const float* __restrict__ s2s,
    const float* __restrict__ SP, const float* __restrict__ SN,
    const float* __restrict__ zP, const float* __restrict__ zN,
    const float* __restrict__ offP, const float* __restrict__ offN,
    const float* __restrict__ offZP, const float* __restrict__ offZN,
    const float* __restrict__ totP, const float* __restrict__ totZP,
    float* __restrict__ out) {
  int wave = (blockIdx.x * blockDim.x + threadIdx.x) >> 6;
  int lane = threadIdx.x & 63;
  int i = wave;
  float s1v = s1[i];
  float t = -s1v;
  // k = first sorted index with s2s[r] > t  (P = [k, NN), N = [0, k))
  int lo = 0, hi = NN;
  while (lo < hi) {
    int mid = (lo + hi) >> 1;
    if (s2s[mid] <= t) lo = mid + 1; else hi = mid;
  }
  int k = lo;
  float wP = expf(s1v);
  float wN = expf(SLOPE * s1v);
  float FPk = 0.f, FNk = 0.f, ZPk = 0.f, ZNk = 0.f;
  if (k > 0) {
    int r = k - 1, c = r / CL;
    FPk = offP[c * DD + lane] + SP[r * DD + lane];
    FNk = offN[c * DD + lane] + SN[r * DD + lane];
    ZPk = offZP[c] + zP[r];
    ZNk = offZN[c] + zN[r];
  }
  float num = wP * (totP[lane] - FPk) + wN * FNk;
  float den = wP * (totZP[0] - ZPk) + wN * ZNk;
  out[i * DD + lane] = num / den;
}

extern "C" void kernel_launch(void* const* d_in, const int* in_sizes, int n_in,
                              void* d_out, int out_size, void* d_ws, size_t ws_size,
                              hipStream_t stream) {
  const float* x = (const float*)d_in[0];
  const float* W = (const float*)d_in[1];
  const float* a = (const float*)d_in[2];
  float* out = (float*)d_out;

  float* ws = (float*)d_ws;
  float* xt   = ws;                 // NN*DD
  float* s1   = xt + NN * DD;       // NN
  float* s2   = s1 + NN;            // NN
  float* s2s  = s2 + NN;            // NN
  int*   perm = (int*)(s2s + NN);   // NN
  float* SP   = (float*)(perm + NN);// NN*DD
  float* SN   = SP + NN * DD;       // NN*DD
  float* zP   = SN + NN * DD;       // NN
  float* zN   = zP + NN;            // NN
  float* offP = zN + NN;            // CH*DD
  float* offN = offP + CH * DD;     // CH*DD
  float* offZP = offN + CH * DD;    // CH
  float* offZN = offZP + CH;        // CH
  float* totP  = offZN + CH;        // DD
  float* totZP = totP + DD;         // 1

  k1_xt<<<NN / 16, 256, 0, stream>>>(x, W, a, xt, s1, s2);
  k2_sort<<<1, 1024, 0, stream>>>(s2, s2s, perm);
  k3_scan<<<CH, 64, 0, stream>>>(xt, s2s, perm, SP, SN, zP, zN);
  k4_off<<<1, 64, 0, stream>>>(SP, SN, zP, zN, offP, offN, offZP, offZN, totP, totZP);
  k5_out<<<NN / 4, 256, 0, stream>>>(s1, s2s, SP, SN, zP, zN,
                                     offP, offN, offZP, offZN, totP, totZP, out);
}

// Round 2
// 86.503 us; speedup vs baseline: 1.5856x; 1.5856x over previous
//
#include <hip/hip_runtime.h>

#define NN 4096
#define HID 512
#define DD 64
#define SLOPE 0.2f
#define CH 64
#define CL 64   // NN/CH

// ---------------- k1: xt = x@W (f32, LDS-staged W), s1 = xt@a1, s2 = xt@a2 ----
// 4 rows per wave concurrently: one LDS read of W feeds 4 FMAs (x via s_load).
__global__ __launch_bounds__(256) void k1_xt(
    const float* __restrict__ x, const float* __restrict__ W,
    const float* __restrict__ a,
    float* __restrict__ xt, float* __restrict__ s1, float* __restrict__ s2) {
  __shared__ float Wl[HID * DD];           // 128 KiB
  int tid = threadIdx.x;
  const float4* W4 = (const float4*)W;
  float4* Wl4 = (float4*)Wl;
#pragma unroll
  for (int u = 0; u < (HID * DD / 4) / 256; ++u)
    Wl4[u * 256 + tid] = W4[u * 256 + tid];
  __syncthreads();
  int wave = tid >> 6, lane = tid & 63;
  int i0 = blockIdx.x * 16 + wave * 4;     // 4 rows per wave
  const float* xr0 = x + (i0 + 0) * HID;   // wave-uniform -> scalar loads
  const float* xr1 = x + (i0 + 1) * HID;
  const float* xr2 = x + (i0 + 2) * HID;
  const float* xr3 = x + (i0 + 3) * HID;
  float acc0 = 0.f, acc1 = 0.f, acc2 = 0.f, acc3 = 0.f;
#pragma unroll 8
  for (int k = 0; k < HID; ++k) {
    float w = Wl[k * DD + lane];
    acc0 = fmaf(xr0[k], w, acc0);
    acc1 = fmaf(xr1[k], w, acc1);
    acc2 = fmaf(xr2[k], w, acc2);
    acc3 = fmaf(xr3[k], w, acc3);
  }
  xt[(i0 + 0) * DD + lane] = acc0;
  xt[(i0 + 1) * DD + lane] = acc1;
  xt[(i0 + 2) * DD + lane] = acc2;
  xt[(i0 + 3) * DD + lane] = acc3;
  float a1 = a[lane], a2 = a[DD + lane];
  float p10 = acc0 * a1, p20 = acc0 * a2;
  float p11 = acc1 * a1, p21 = acc1 * a2;
  float p12 = acc2 * a1, p22 = acc2 * a2;
  float p13 = acc3 * a1, p23 = acc3 * a2;
#pragma unroll
  for (int off = 32; off >= 1; off >>= 1) {
    p10 += __shfl_xor(p10, off, 64); p20 += __shfl_xor(p20, off, 64);
    p11 += __shfl_xor(p11, off, 64); p21 += __shfl_xor(p21, off, 64);
    p12 += __shfl_xor(p12, off, 64); p22 += __shfl_xor(p22, off, 64);
    p13 += __shfl_xor(p13, off, 64); p23 += __shfl_xor(p23, off, 64);
  }
  if (lane == 0) {
    s1[i0 + 0] = p10; s2[i0 + 0] = p20;
    s1[i0 + 1] = p11; s2[i0 + 1] = p21;
    s1[i0 + 2] = p12; s2[i0 + 2] = p22;
    s1[i0 + 3] = p13; s2[i0 + 3] = p23;
  }
}

// ---------------- k2: rank-by-counting "sort" (replaces bitonic) -------------
// 64 blocks x 8 waves. Lane owns element e = blk*64+lane (all 8 waves mirror);
// wave w counts keys < key[e] in slice [w*512, w*512+512); combine in LDS.
__global__ __launch_bounds__(512) void k2_rank(
    const float* __restrict__ s2, float* __restrict__ s2s, int* __restrict__ perm) {
  __shared__ float keys[NN];    // 16 KiB
  __shared__ int pc[8][64];
  int tid = threadIdx.x;
  const float4* s4 = (const float4*)s2;
  float4* kk = (float4*)keys;
#pragma unroll
  for (int u = 0; u < NN / 4 / 512; ++u)
    kk[u * 512 + tid] = s4[u * 512 + tid];
  __syncthreads();
  int wave = tid >> 6, lane = tid & 63;
  int e = blockIdx.x * 64 + lane;
  float ke = keys[e];
  int q0 = wave * (NN / 8);
  int cnt = 0;
#pragma unroll 8
  for (int q = q0; q < q0 + NN / 8; ++q) {
    float kq = keys[q];                     // uniform addr -> broadcast
    cnt += (kq < ke || (kq == ke && q < e)) ? 1 : 0;
  }
  pc[wave][lane] = cnt;
  __syncthreads();
  if (wave == 0) {
    int rank = 0;
#pragma unroll
    for (int w = 0; w < 8; ++w) rank += pc[w][lane];
    s2s[rank] = ke;
    perm[rank] = e;
  }
}

// ---------------- k3: within-chunk inclusive scans (sorted order) ------------
// Stage exp() weights + permuted row offsets in LDS first so the scan loop's
// global loads pipeline; only the FMA accumulate is serial.
__global__ __launch_bounds__(64) void k3_scan(
    const float* __restrict__ xt, const float* __restrict__ s2s,
    const int* __restrict__ perm,
    float* __restrict__ SP, float* __restrict__ SN,
    float* __restrict__ zP, float* __restrict__ zN) {
  int lane = threadIdx.x;
  int r0 = blockIdx.x * CL;
  __shared__ float evP[CL], evN[CL];
  __shared__ int pm[CL];
  float sv = s2s[r0 + lane];
  evP[lane] = expf(sv);
  evN[lane] = expf(SLOPE * sv);
  pm[lane] = perm[r0 + lane] * DD;
  __syncthreads();
  float aP = 0.f, aN = 0.f, aZP = 0.f, aZN = 0.f;
#pragma unroll 8
  for (int q = 0; q < CL; ++q) {
    int r = r0 + q;
    float eP = evP[q], eN = evN[q];
    float xv = xt[pm[q] + lane];
    aP = fmaf(eP, xv, aP);
    aN = fmaf(eN, xv, aN);
    aZP += eP; aZN += eN;
    SP[r * DD + lane] = aP;
    SN[r * DD + lane] = aN;
    if (lane == 0) { zP[r] = aZP; zN[r] = aZN; }
  }
}

// ---------------- k4: exclusive scan of chunk totals -------------------------
__global__ __launch_bounds__(64) void k4_off(
    const float* __restrict__ SP, const float* __restrict__ SN,
    const float* __restrict__ zP, const float* __restrict__ zN,
    float* __restrict__ offP, float* __restrict__ offN,
    float* __restrict__ offZP, float* __restrict__ offZN,
    float* __restrict__ totP, float* __restrict__ totZP) {
  int lane = threadIdx.x;
  float rP = 0.f, rN = 0.f, rZP = 0.f, rZN = 0.f;
#pragma unroll 8
  for (int c = 0; c < CH; ++c) {
    offP[c * DD + lane] = rP;
    offN[c * DD + lane] = rN;
    if (lane == 0) { offZP[c] = rZP; offZN[c] = rZN; }
    int last = c * CL + CL - 1;
    rP += SP[last * DD + lane];
    rN += SN[last * DD + lane];
    rZP += zP[last];
    rZN += zN[last];
  }
  totP[lane] = rP;
  if (lane == 0) totZP[0] = rZP;
}

// ---------------- k5: per-row binary search + closed-form output -------------
__global__ __launch_bounds__(256) void k5_out(
    const float* __restrict__ s1, const float* __restrict__ s2s,
    const float* __restrict__ SP, const float* __restrict__ SN,
    const float* __restrict__ zP, const float* __restrict__ zN,
    const float* __restrict__ offP, const float* __restrict__ offN,
    const float* __restrict__ offZP, const float* __restrict__ offZN,
    const float* __restrict__ totP, const float* __restrict__ totZP,
    float* __restrict__ out) {
  int wave = (blockIdx.x * blockDim.x + threadIdx.x) >> 6;
  int lane = threadIdx.x & 63;
  int i = wave;
  float s1v = s1[i];
  float t = -s1v;
  // k = first sorted index with s2s[r] > t  (P = [k, NN), N = [0, k))
  int lo = 0, hi = NN;
  while (lo < hi) {
    int mid = (lo + hi) >> 1;
    if (s2s[mid] <= t) lo = mid + 1; else hi = mid;
  }
  int k = lo;
  float wP = expf(s1v);
  float wN = expf(SLOPE * s1v);
  float FPk = 0.f, FNk = 0.f, ZPk = 0.f, ZNk = 0.f;
  if (k > 0) {
    int r = k - 1, c = r / CL;
    FPk = offP[c * DD + lane] + SP[r * DD + lane];
    FNk = offN[c * DD + lane] + SN[r * DD + lane];
    ZPk = offZP[c] + zP[r];
    ZNk = offZN[c] + zN[r];
  }
  float num = wP * (totP[lane] - FPk) + wN * FNk;
  float den = wP * (totZP[0] - ZPk) + wN * ZNk;
  out[i * DD + lane] = num / den;
}

extern "C" void kernel_launch(void* const* d_in, const int* in_sizes, int n_in,
                              void* d_out, int out_size, void* d_ws, size_t ws_size,
                              hipStream_t stream) {
  const float* x = (const float*)d_in[0];
  const float* W = (const float*)d_in[1];
  const float* a = (const float*)d_in[2];
  float* out = (float*)d_out;

  float* ws = (float*)d_ws;
  float* xt   = ws;                 // NN*DD
  float* s1   = xt + NN * DD;       // NN
  float* s2   = s1 + NN;            // NN
  float* s2s  = s2 + NN;            // NN
  int*   perm = (int*)(s2s + NN);   // NN
  float* SP   = (float*)(perm + NN);// NN*DD
  float* SN   = SP + NN * DD;       // NN*DD
  float* zP   = SN + NN * DD;       // NN
  float* zN   = zP + NN;            // NN
  float* offP = zN + NN;            // CH*DD
  float* offN = offP + CH * DD;     // CH*DD
  float* offZP = offN + CH * DD;    // CH
  float* offZN = offZP + CH;        // CH
  float* totP  = offZN + CH;        // DD
  float* totZP = totP + DD;         // 1

  k1_xt<<<NN / 16, 256, 0, stream>>>(x, W, a, xt, s1, s2);
  k2_rank<<<NN / 64, 512, 0, stream>>>(s2, s2s, perm);
  k3_scan<<<CH, 64, 0, stream>>>(xt, s2s, perm, SP, SN, zP, zN);
  k4_off<<<1, 64, 0, stream>>>(SP, SN, zP, zN, offP, offN, offZP, offZN, totP, totZP);
  k5_out<<<NN / 4, 256, 0, stream>>>(s1, s2s, SP, SN, zP, zN,
                                     offP, offN, offZP, offZN, totP, totZP, out);
}